// Round 2
// 220.945 us; speedup vs baseline: 1.0001x; 1.0001x over previous
//
#include <hip/hip_runtime.h>

// z = x @ W.T - b (65536x512 @ (256x512)^T) -> row-wise projection onto
// {y: |1^T y|<=S, ||y||^2<=R2}. Projection is affine per row (y = a*z + b0),
// fused into the GEMM epilogue via per-row (t, zz) reductions.
//
// R3 restructure vs R2 (memory-bound, ~2x above BW roofline):
//  - B tile double-buffered (glds into alternating halves), A reg-staged with
//    issue-early/write-late split (T14): next tile's 4 B-glds + 4 A-loads stay
//    in flight across BOTH barriers of every K-iteration.
//  - raw s_barrier + counted "s_waitcnt vmcnt(4)" (never 0 in steady state)
//    replaces __syncthreads()'s full vmcnt(0)/lgkmcnt(0) drain.
//  - A tile pad (LDA=72) replaced by XOR swizzle (byte ^= (row&7)<<4) so
//    LDS = 16KB A + 2x32KB B = 80KB/block -> still 2 blocks/CU (16 waves/CU).
// (R4 = R3 resubmitted verbatim: round-1 failure was container acquisition,
//  no bench/profile evidence against the kernel; audit found no hazard.)

typedef __bf16 bf16x8 __attribute__((ext_vector_type(8)));
typedef float f32x4 __attribute__((ext_vector_type(4)));

#define BM 128
#define BN 256
#define BK 64
#define THREADS 512

__device__ __forceinline__ unsigned short f2bf(float f) {
    unsigned u = __builtin_bit_cast(unsigned, f);
    u += 0x7fffu + ((u >> 16) & 1u);     // RNE
    return (unsigned short)(u >> 16);
}

// one-time: W fp32 [256][512] -> bf16 row-major in workspace
__global__ void wconv_kernel(const float* __restrict__ W,
                             unsigned short* __restrict__ Wb) {
    int i = (blockIdx.x * 256 + threadIdx.x) * 4;
    float4 v = *(const float4*)(W + i);
    ushort4 h;
    h.x = f2bf(v.x); h.y = f2bf(v.y); h.z = f2bf(v.z); h.w = f2bf(v.w);
    *(ushort4*)(Wb + i) = h;
}

__global__ __launch_bounds__(THREADS, 4)
void proj_gemm_kernel(const float* __restrict__ x,
                      const unsigned short* __restrict__ Wb,
                      const float* __restrict__ b,
                      float* __restrict__ out) {
    __shared__ alignas(16) unsigned short Abuf[BM * BK];        // 16384 B, XOR-swizzled
    __shared__ alignas(16) unsigned short Bbuf[2][BN * BK];     // 2 x 32768 B, chunk-swizzled

    const int tid  = threadIdx.x;
    const int lane = tid & 63;
    const int wv   = tid >> 6;        // 0..7
    const int wm   = wv >> 2;         // m-half (0..1)
    const int wn   = wv & 3;          // n-quarter (0..3)
    const int ln   = lane & 15;
    const int quad = lane >> 4;
    const int m0   = blockIdx.x * BM;

    // A staging coords: 128 rows x 16 float4-chunks, 512 threads -> 4 rows each
    const int arow = tid >> 4;        // 0..31
    const int kq   = tid & 15;
    const float* xbase = x + (long)(m0 + arow) * 512 + kq * 4;

    // A LDS write byte offsets (fixed per thread): row*128 + kq*8, XOR-swizzled
    unsigned awb[4];
    #pragma unroll
    for (int p = 0; p < 4; ++p) {
        const int row = arow + p * 32;
        awb[p] = (unsigned)((row * 128 + kq * 8) ^ ((row & 7) << 4));
    }

    // B staging via global_load_lds: issue j covers flat 16B-chunks
    // f = (wv*4+j)*64 + lane; r = f>>3; swizzled col-chunk cg = (lane&7)^(lane>>3).
    const int b_r0 = wv * 32 + (lane >> 3);          // row for j=0; +8 per j
    const int b_cg = (lane & 7) ^ (lane >> 3);       // 16B chunk within row

    f32x4 acc[4][4];
    #pragma unroll
    for (int mi = 0; mi < 4; ++mi)
        #pragma unroll
        for (int ni = 0; ni < 4; ++ni)
            acc[mi][ni] = (f32x4){0.f, 0.f, 0.f, 0.f};

    float4 areg[4];

    // ---- staging helpers --------------------------------------------------
    auto issue_B = [&](int kt, int buf) {
        const int k0 = kt * BK;
        #pragma unroll
        for (int j = 0; j < 4; ++j) {
            const unsigned short* src =
                Wb + (long)(b_r0 + j * 8) * 512 + k0 + b_cg * 8;
            __builtin_amdgcn_global_load_lds(
                (const __attribute__((address_space(1))) void*)src,
                (__attribute__((address_space(3))) void*)(unsigned long)(unsigned int)
                    (unsigned long)(uintptr_t)&Bbuf[buf][(wv * 4 + j) * 512],
                16, 0, 0);
        }
    };
    auto load_A = [&](int kt) {
        const int k0 = kt * BK;
        #pragma unroll
        for (int p = 0; p < 4; ++p)
            areg[p] = *(const float4*)(xbase + (long)p * 32 * 512 + k0);
    };
    auto write_A = [&]() {
        #pragma unroll
        for (int p = 0; p < 4; ++p) {
            ushort4 h;
            h.x = f2bf(areg[p].x); h.y = f2bf(areg[p].y);
            h.z = f2bf(areg[p].z); h.w = f2bf(areg[p].w);
            *(ushort4*)((char*)Abuf + awb[p]) = h;
        }
    };

    // ---- prologue: tile 0 in flight ---------------------------------------
    issue_B(0, 0);
    load_A(0);

    // ---- main K-loop: 8 tiles, B double-buffered, counted vmcnt ------------
    // steady-state in flight across compute: B(t+1)[4 glds] + A(t+1)[4 loads]
    for (int kt = 0; kt < 8; ++kt) {
        const int cur = kt & 1;
        if (kt < 7) {
            issue_B(kt + 1, cur ^ 1);
            // retire B(t)+A(t) (oldest 8 of 12); keep B(t+1) in flight
            asm volatile("s_waitcnt vmcnt(4)" ::: "memory");
        } else {
            asm volatile("s_waitcnt vmcnt(0)" ::: "memory");
        }
        write_A();                       // fp32->bf16 -> swizzled LDS
        if (kt < 7) load_A(kt + 1);      // issue next A loads (stay in flight)
        asm volatile("s_waitcnt lgkmcnt(0)" ::: "memory");  // ds_writes visible
        __builtin_amdgcn_s_barrier();

        #pragma unroll
        for (int ks = 0; ks < 2; ++ks) {
            bf16x8 bf[4];
            #pragma unroll
            for (int ni = 0; ni < 4; ++ni) {
                const int r  = wn * 64 + ni * 16 + ln;
                const int cc = (ks * 4 + quad) ^ (ln & 7);   // un-swizzle
                bf[ni] = *(const bf16x8*)&Bbuf[cur][r * 64 + cc * 8];
            }
            #pragma unroll
            for (int mi = 0; mi < 4; ++mi) {
                const int row = wm * 64 + mi * 16 + ln;
                const unsigned arb =
                    (unsigned)(row * 128 + ((((ks << 2) | quad) ^ (ln & 7)) << 4));
                bf16x8 af = *(const bf16x8*)((const char*)Abuf + arb);
                #pragma unroll
                for (int ni = 0; ni < 4; ++ni)
                    acc[mi][ni] = __builtin_amdgcn_mfma_f32_16x16x32_bf16(
                        af, bf[ni], acc[mi][ni], 0, 0, 0);
            }
        }
        // all LDS reads of this tile retired before next tile's overwrite
        asm volatile("s_waitcnt lgkmcnt(0)" ::: "memory");
        __builtin_amdgcn_s_barrier();
    }

    // bias before row reductions
    float bb[4];
    #pragma unroll
    for (int ni = 0; ni < 4; ++ni) bb[ni] = b[wn * 64 + ni * 16 + ln];
    #pragma unroll
    for (int mi = 0; mi < 4; ++mi)
        #pragma unroll
        for (int ni = 0; ni < 4; ++ni)
            #pragma unroll
            for (int r = 0; r < 4; ++r)
                acc[mi][ni][r] -= bb[ni];

    __syncthreads();
    float* P  = (float*)Abuf;         // 128 rows x {4 waves x (t,zz)} = 4 KB
    float* AB = P + 128 * 8;          // 128 x (alpha,beta)

    // per-row partials over this wave's 64 cols (cols indexed by ni,ln)
    #pragma unroll
    for (int mi = 0; mi < 4; ++mi) {
        #pragma unroll
        for (int r = 0; r < 4; ++r) {
            float s1 = 0.f, s2 = 0.f;
            #pragma unroll
            for (int ni = 0; ni < 4; ++ni) {
                float v = acc[mi][ni][r];
                s1 += v; s2 += v * v;
            }
            #pragma unroll
            for (int off = 1; off < 16; off <<= 1) {
                s1 += __shfl_xor(s1, off, 64);
                s2 += __shfl_xor(s2, off, 64);
            }
            if (ln == 0) {
                int row = wm * 64 + mi * 16 + quad * 4 + r;
                P[row * 8 + wn * 2 + 0] = s1;
                P[row * 8 + wn * 2 + 1] = s2;
            }
        }
    }
    __syncthreads();

    // one thread per row: KKT case analysis -> (alpha, beta)
    if (tid < 128) {
        int row = tid;
        float t  = P[row*8+0] + P[row*8+2] + P[row*8+4] + P[row*8+6];
        float zz = P[row*8+1] + P[row*8+3] + P[row*8+5] + P[row*8+7];
        const float S = 0.1f, R2 = 0.02f, nf = 256.f, inv_n = 1.f / 256.f;
        float tc    = fminf(fmaxf(t, -S), S);
        float beta1 = (tc - t) * inv_n;
        float ny1   = zz + 2.f * beta1 * t + nf * beta1 * beta1;
        float alpha, beta;
        if (ny1 <= R2) {
            alpha = 1.f; beta = beta1;
        } else {
            float znorm = sqrtf(fmaxf(zz, 1e-12f));
            float scale = fminf(1.f, 0.14142135623730951f / znorm);
            if (fabsf(t) * scale <= S) {
                alpha = scale; beta = 0.f;
            } else {
                float denom = fmaxf(nf * zz - t * t, 1e-12f);
                float c  = sqrtf(5.11f / denom);             // n*R2 - S^2
                float sp = (t > 0.f) ? S : ((t < 0.f) ? -S : 0.f);
                alpha = c; beta = (sp - c * t) * inv_n;
            }
        }
        AB[row*2+0] = alpha;
        AB[row*2+1] = beta;
    }
    __syncthreads();

    // apply y = alpha*z + beta, store
    #pragma unroll
    for (int mi = 0; mi < 4; ++mi) {
        #pragma unroll
        for (int r = 0; r < 4; ++r) {
            int row = wm * 64 + mi * 16 + quad * 4 + r;
            float alpha = AB[row*2+0];
            float beta  = AB[row*2+1];
            float* orow = out + (long)(m0 + row) * 256 + wn * 64 + ln;
            #pragma unroll
            for (int ni = 0; ni < 4; ++ni)
                orow[ni*16] = alpha * acc[mi][ni][r] + beta;
        }
    }
}

extern "C" void kernel_launch(void* const* d_in, const int* in_sizes, int n_in,
                              void* d_out, int out_size, void* d_ws, size_t ws_size,
                              hipStream_t stream) {
    const float* x = (const float*)d_in[0];   // [65536, 512]
    const float* W = (const float*)d_in[1];   // [256, 512]
    const float* b = (const float*)d_in[2];   // [256]
    float* out = (float*)d_out;               // [65536, 256]
    unsigned short* Wb = (unsigned short*)d_ws; // 256KB bf16 W

    const int Dout = in_sizes[2];             // 256
    const int Din  = in_sizes[1] / Dout;      // 512
    const int Btot = in_sizes[0] / Din;       // 65536

    wconv_kernel<<<(Dout * Din) / (256 * 4), 256, 0, stream>>>(W, Wb);
    proj_gemm_kernel<<<Btot / BM, THREADS, 0, stream>>>(x, Wb, b, out);
}